// Round 1
// baseline (11.746 us; speedup 1.0000x reference)
//
#include <hip/hip_runtime.h>

#define BATCH 2048
#define NUM_CLASSES 50000
#define FEAT_DIM 256
#define CLAMP_MIN 1e-12f
#define CLAMP_MAX 1e12f

// One wave (64 lanes) per batch row: lane i handles elements [4i, 4i+4) of the
// 256-dim row. Gathered center row is contiguous (1 KB) -> coalesced float4.
__global__ void __launch_bounds__(64)
row_dist_kernel(const float* __restrict__ x,
                const int* __restrict__ labels,
                const float* __restrict__ centers,
                float* __restrict__ row_out) {
    const int b = blockIdx.x;
    const int lane = threadIdx.x;  // 0..63
    const int lab = labels[b];

    const float4 xv = *reinterpret_cast<const float4*>(
        x + (size_t)b * FEAT_DIM + lane * 4);
    const float4 cv = *reinterpret_cast<const float4*>(
        centers + (size_t)lab * FEAT_DIM + lane * 4);

    const float dx = xv.x - cv.x;
    const float dy = xv.y - cv.y;
    const float dz = xv.z - cv.z;
    const float dw = xv.w - cv.w;
    float s = dx * dx + dy * dy + dz * dz + dw * dw;

    // wave64 butterfly reduce
    #pragma unroll
    for (int off = 32; off > 0; off >>= 1)
        s += __shfl_down(s, off, 64);

    if (lane == 0) {
        s = fminf(fmaxf(s, CLAMP_MIN), CLAMP_MAX);
        row_out[b] = s;
    }
}

// Deterministic single-block reduction of BATCH partials -> scalar loss.
__global__ void __launch_bounds__(256)
final_reduce_kernel(const float* __restrict__ row_out, float* __restrict__ out) {
    __shared__ float sm[256];
    const int t = threadIdx.x;
    float s = 0.f;
    #pragma unroll
    for (int i = 0; i < BATCH / 256; ++i)
        s += row_out[t + i * 256];
    sm[t] = s;
    __syncthreads();
    #pragma unroll
    for (int off = 128; off > 0; off >>= 1) {
        if (t < off) sm[t] += sm[t + off];
        __syncthreads();
    }
    if (t == 0) {
        // masked zeros clamp to CLAMP_MIN: B*(C-1) of them, then / B
        const double masked = (double)(NUM_CLASSES - 1) * 1e-12;  // per-row share
        out[0] = (float)((double)sm[0] / (double)BATCH + masked);
    }
}

extern "C" void kernel_launch(void* const* d_in, const int* in_sizes, int n_in,
                              void* d_out, int out_size, void* d_ws, size_t ws_size,
                              hipStream_t stream) {
    const float* x       = (const float*)d_in[0];
    const int*   labels  = (const int*)d_in[1];
    const float* centers = (const float*)d_in[2];
    float* out = (float*)d_out;
    float* ws  = (float*)d_ws;  // BATCH floats of scratch

    row_dist_kernel<<<BATCH, 64, 0, stream>>>(x, labels, centers, ws);
    final_reduce_kernel<<<1, 256, 0, stream>>>(ws, out);
}

// Round 2
// 11.403 us; speedup vs baseline: 1.0301x; 1.0301x over previous
//
#include <hip/hip_runtime.h>

#define BATCH 2048
#define NUM_CLASSES 50000
#define FEAT_DIM 256
#define CLAMP_MIN 1e-12f
#define CLAMP_MAX 1e12f

// 512 blocks x 256 threads = 4 waves/block, one batch row per wave.
// Lane i of a wave handles elements [4i, 4i+4) of the 256-dim row.
// Gathered center row is contiguous (1 KB) -> fully coalesced float4.
__global__ void __launch_bounds__(256)
row_dist_kernel(const float* __restrict__ x,
                const int* __restrict__ labels,
                const float* __restrict__ centers,
                float* __restrict__ row_out) {
    const int wave = threadIdx.x >> 6;          // 0..3
    const int lane = threadIdx.x & 63;          // 0..63
    const int b = (blockIdx.x << 2) + wave;     // row index, 0..2047

    // Wave-uniform label -> scalar load path for the gather base.
    const int lab = __builtin_amdgcn_readfirstlane(labels[b]);

    // x load and label load are independent; center gather depends on label.
    const float4 xv = *reinterpret_cast<const float4*>(
        x + (size_t)b * FEAT_DIM + lane * 4);
    const float4 cv = *reinterpret_cast<const float4*>(
        centers + (size_t)lab * FEAT_DIM + lane * 4);

    const float dx = xv.x - cv.x;
    const float dy = xv.y - cv.y;
    const float dz = xv.z - cv.z;
    const float dw = xv.w - cv.w;
    float s = dx * dx + dy * dy + dz * dz + dw * dw;

    // wave64 reduce, 6 steps
    #pragma unroll
    for (int off = 32; off > 0; off >>= 1)
        s += __shfl_down(s, off, 64);

    if (lane == 0) {
        s = fminf(fmaxf(s, CLAMP_MIN), CLAMP_MAX);
        row_out[b] = s;
    }
}

// Single-wave deterministic final reduction: 64 lanes x 8 float4 = 2048 floats.
// No LDS, no __syncthreads; 8 independent loads overlap their latency.
__global__ void __launch_bounds__(64)
final_reduce_kernel(const float* __restrict__ row_out, float* __restrict__ out) {
    const int lane = threadIdx.x;  // 0..63
    float s = 0.f;
    #pragma unroll
    for (int j = 0; j < 8; ++j) {
        const float4 v = *reinterpret_cast<const float4*>(
            row_out + j * 256 + lane * 4);
        s += v.x + v.y + v.z + v.w;
    }
    #pragma unroll
    for (int off = 32; off > 0; off >>= 1)
        s += __shfl_down(s, off, 64);

    if (lane == 0) {
        // masked zeros clamp to CLAMP_MIN: (C-1) of them per row, then / B
        const double masked = (double)(NUM_CLASSES - 1) * 1e-12;
        out[0] = (float)((double)s / (double)BATCH + masked);
    }
}

extern "C" void kernel_launch(void* const* d_in, const int* in_sizes, int n_in,
                              void* d_out, int out_size, void* d_ws, size_t ws_size,
                              hipStream_t stream) {
    const float* x       = (const float*)d_in[0];
    const int*   labels  = (const int*)d_in[1];
    const float* centers = (const float*)d_in[2];
    float* out = (float*)d_out;
    float* ws  = (float*)d_ws;  // BATCH floats of scratch

    row_dist_kernel<<<BATCH / 4, 256, 0, stream>>>(x, labels, centers, ws);
    final_reduce_kernel<<<1, 64, 0, stream>>>(ws, out);
}